// Round 1
// baseline (78.034 us; speedup 1.0000x reference)
//
#include <hip/hip_runtime.h>

#define T_LEN 41
#define K_LEN 28
#define GROUPS 8                        // 256 threads / 32 lanes
#define RPG 2                           // rows per 32-lane group
#define ROWS_PER_BLOCK (GROUPS * RPG)   // 16
#define BLOCK 256
#define P_STRIDE 45                     // [0,1]=pad, [2..42]=t=0..40, [43,44]=pad

// DPP-based inclusive scans (VALU only). row_shr:d = 0x110|d ;
// row_bcast:15 = 0x142 (lane15 -> lanes16..31 of each 32-half, row_mask 0xA).
// bound_ctrl=false, old = identity (0 for add, -inf for max).
#define DPP_ADD(x, ctrl, rmask)                                                  \
    x += __int_as_float(__builtin_amdgcn_update_dpp(                             \
        0, __float_as_int(x), ctrl, rmask, 0xF, false))
#define DPP_MAX(x, ctrl, rmask)                                                  \
    x = fmaxf(x, __int_as_float(__builtin_amdgcn_update_dpp(                     \
        (int)0xFF800000, __float_as_int(x), ctrl, rmask, 0xF, false)))

#define SCAN32_ADD(x)  do { DPP_ADD(x,0x111,0xF); DPP_ADD(x,0x112,0xF);          \
                            DPP_ADD(x,0x114,0xF); DPP_ADD(x,0x118,0xF);          \
                            DPP_ADD(x,0x142,0xA); } while (0)
#define SCAN32_MAX(x)  do { DPP_MAX(x,0x111,0xF); DPP_MAX(x,0x112,0xF);          \
                            DPP_MAX(x,0x114,0xF); DPP_MAX(x,0x118,0xF);          \
                            DPP_MAX(x,0x142,0xA); } while (0)
#define SCAN16_ADD(x)  do { DPP_ADD(x,0x111,0xF); DPP_ADD(x,0x112,0xF);          \
                            DPP_ADD(x,0x114,0xF); DPP_ADD(x,0x118,0xF); } while (0)
#define SCAN16_MAX(x)  do { DPP_MAX(x,0x111,0xF); DPP_MAX(x,0x112,0xF);          \
                            DPP_MAX(x,0x114,0xF); DPP_MAX(x,0x118,0xF); } while (0)

// broadcast lane `sel` of each 32-lane group to all 32 lanes
#define BCAST32(x, sel) __int_as_float(                                          \
    __builtin_amdgcn_ds_swizzle(__float_as_int(x), ((sel) << 5)))

__global__ __launch_bounds__(BLOCK) void pil_kernel(
    const float* __restrict__ instock,
    const float* __restrict__ futured,
    const float* __restrict__ lead_pred,
    float* __restrict__ out, int B)
{
    // fused P = FC + OC, one float per time step, zero pads both ends.
    __shared__ float lds[GROUPS][RPG][P_STRIDE];

    const int g    = threadIdx.x >> 5;
    const int lane = threadIdx.x & 31;
    const int row0 = blockIdx.x * ROWS_PER_BLOCK + g * RPG;

    float fa[RPG], ga[RPG], fb[RPG], gb[RPG], lead[RPG];

    // issue all global loads for both rows up front (8-10 loads in flight)
    #pragma unroll
    for (int r = 0; r < RPG; ++r) {
        const float* __restrict__ f = futured + (row0 + r) * T_LEN;
        const float* __restrict__ s = instock + (row0 + r) * T_LEN;
        const float fv = f[lane];
        const float sv = s[lane];
        float fbv = 0.f, sbv = 0.f;
        if (lane < T_LEN - 32) { fbv = f[32 + lane]; sbv = s[32 + lane]; }
        lead[r] = lead_pred[row0 + r];
        fa[r] = fv; ga[r] = sv - fv;      // scan (s-f) directly: D = IC - FC
        fb[r] = fbv; gb[r] = sbv - fbv;
    }

    // FC = cumsum(f); D = cumsum(s-f) — two independent chains per row,
    // 2 rows interleave in the scheduler.
    #pragma unroll
    for (int r = 0; r < RPG; ++r) SCAN32_ADD(fa[r]);
    #pragma unroll
    for (int r = 0; r < RPG; ++r) SCAN32_ADD(ga[r]);

    float ic41[RPG];
    #pragma unroll
    for (int r = 0; r < RPG; ++r) {
        const float fc31 = BCAST32(fa[r], 31);   // FC[31]
        const float gc31 = BCAST32(ga[r], 31);   // D[31] (pre-relu, pre-max)
        SCAN16_ADD(fb[r]);
        SCAN16_ADD(gb[r]);
        fb[r] += fc31;                           // FC tail (t=32..40 in lanes 0..8)
        gb[r] += gc31;                           // D  tail
        ic41[r] = BCAST32(fb[r] + gb[r], 8);     // IC[40] = FC[40] + D[40]
    }

    // OC = cummax([relu(D0), D1, ...])
    #pragma unroll
    for (int r = 0; r < RPG; ++r) {
        if (lane == 0) ga[r] = fmaxf(ga[r], 0.f);
        SCAN32_MAX(ga[r]);
    }
    #pragma unroll
    for (int r = 0; r < RPG; ++r) {
        const float m31 = BCAST32(ga[r], 31);    // OC[31]
        SCAN16_MAX(gb[r]);
        gb[r] = fmaxf(gb[r], m31);               // OC tail
    }

    // stash P = FC + OC (+ zero pads). Producer and consumer are the SAME wave;
    // DS ops execute in order per wave, so no __syncthreads is needed.
    #pragma unroll
    for (int r = 0; r < RPG; ++r) {
        lds[g][r][2 + lane] = fa[r] + ga[r];
        if (lane < T_LEN - 32) {
            lds[g][r][34 + lane] = fb[r] + gb[r];
        } else if (lane < 13) {
            // lanes 9,10 -> slots 0,1 ; lanes 11,12 -> slots 43,44
            const int slot = (lane < 11) ? (lane - 9) : (lane + 32);
            lds[g][r][slot] = 0.f;
        }
    }

    // phase B: sigma=0.3 Gaussian -> only taps i = floor(ls)+k+j, j in {-1..2}
    // survive (dropped terms < e^-22); truncation to i in [1,41] matches the
    // reference's own normalization range. Pads make OOB reads return 0; only
    // wsum needs the predicate.
    if (lane < K_LEN) {
        #pragma unroll
        for (int r = 0; r < RPG; ++r) {
            const float ls = fminf(fmaxf(lead[r] * 13.0f + 1.0f, 1.0f), 14.0f);
            const float Ff = floorf(ls);
            const float fr = ls - Ff;
            const int   Fi = (int)Ff;
            const float inv_bw = 1.0f / 0.3f;

            float wsum = 0.f, acc = 0.f;
            #pragma unroll
            for (int j = -1; j <= 2; ++j) {
                const int   i  = Fi + lane + j;            // 1-based time index
                const float dz = ((float)j - fr) * inv_bw;
                const float w  = __expf(-0.5f * dz * dz);
                acc = fmaf(w, lds[g][r][i + 1], acc);      // slot = (i-1)+2
                if (i >= 1 && i <= T_LEN) wsum += w;
            }
            out[(row0 + r) * K_LEN + lane] = ic41[r] - acc / wsum;
        }
    }
}

extern "C" void kernel_launch(void* const* d_in, const int* in_sizes, int n_in,
                              void* d_out, int out_size, void* d_ws, size_t ws_size,
                              hipStream_t stream) {
    const float* instock   = (const float*)d_in[0];
    const float* futured   = (const float*)d_in[1];
    const float* lead_pred = (const float*)d_in[2];
    float* out = (float*)d_out;
    (void)d_ws; (void)ws_size; (void)n_in; (void)out_size;

    const int B = in_sizes[0] / T_LEN;               // 65536
    const int grid = B / ROWS_PER_BLOCK;             // 4096

    pil_kernel<<<grid, BLOCK, 0, stream>>>(instock, futured, lead_pred, out, B);
}